// Round 8
// baseline (528.698 us; speedup 1.0000x reference)
//
#include <hip/hip_runtime.h>
#include <math.h>

#define H 512
#define W 512
#define HW (H * W)
#define NCH 6

__device__ __forceinline__ int reflect_idx(int p, int n) {
    if (p < 0) p = -p;
    if (p >= n) p = 2 * n - 2 - p;
    return p;
}

// ---------------- K1: Sobel (LDS-tiled, 128x8, 4 px/thread interleaved) ----------------
__global__ __launch_bounds__(256) void k_sobel(const float* __restrict__ img,
                                               float* __restrict__ gpart,
                                               float* __restrict__ g,
                                               float* __restrict__ xn,
                                               float* __restrict__ yn) {
    const int SW = 132, SH = 10;
    __shared__ float st[SH * SW];

    int ch = blockIdx.z;
    int bx0 = blockIdx.x * 128, by0 = blockIdx.y * 8;
    int tx = threadIdx.x, ty = threadIdx.y;
    int tid = ty * 32 + tx;
    const float* im = img + (size_t)ch * HW;

    for (int i = tid; i < SH * 130; i += 256) {
        int r = i / 130, c = i - r * 130;
        int yy = by0 - 1 + r, xx = bx0 - 1 + c;
        float v = 0.f;
        if (yy >= 0 && yy < H && xx >= 0 && xx < W) v = im[yy * W + xx];  // zero pad
        st[r * SW + c] = v;
    }
    __syncthreads();

    float bmax = 0.f;
    int y = by0 + ty;
    int r = ty + 1;
    float gm4[4], xr4[4], yr4[4];
#pragma unroll
    for (int k = 0; k < 4; ++k) {
        int c = tx + 32 * k + 1;
        float a00 = st[(r - 1) * SW + c - 1], a01 = st[(r - 1) * SW + c], a02 = st[(r - 1) * SW + c + 1];
        float a10 = st[r * SW + c - 1], a12 = st[r * SW + c + 1];
        float a20 = st[(r + 1) * SW + c - 1], a21 = st[(r + 1) * SW + c], a22 = st[(r + 1) * SW + c + 1];

        float gx = (a02 - a00) + 2.f * (a12 - a10) + (a22 - a20);
        float gy = (a20 - a00) + 2.f * (a21 - a01) + (a22 - a02);

        gx = fmaxf(gx, 1e-12f);
        gy = fmaxf(gy, 1e-12f);
        float d = gx * gx + gy * gy;
        float rq = __builtin_amdgcn_rsqf(d);
        float gm = d * rq;
        float xv = gx * rq, yv = gy * rq;
        const float ct = -4.37113883e-08f;  // cosf(fp32 pi/2); sin = 1.0 exactly
        gm4[k] = gm;
        xr4[k] = xv * ct - yv;
        yr4[k] = yv * ct + xv;
        bmax = fmaxf(bmax, gm);
    }
#pragma unroll
    for (int k = 0; k < 4; ++k) {
        int idx = y * W + bx0 + tx + 32 * k;
        float* gc = g + (size_t)ch * HW;
        float* xc = xn + (size_t)ch * HW;
        float* yc = yn + (size_t)ch * HW;
        gc[idx] = gm4[k];
        xc[idx] = xr4[k];
        yc[idx] = yr4[k];
    }

    __syncthreads();
    st[tid] = bmax;
    __syncthreads();
    for (int s = 128; s > 0; s >>= 1) {
        if (tid < s) st[tid] = fmaxf(st[tid], st[tid + s]);
        __syncthreads();
    }
    if (tid == 0) gpart[ch * 256 + blockIdx.y * 4 + blockIdx.x] = st[0];
}

// ---------------- fused 3-iteration ETF: wave-autonomous tiles ----------------
#define SS 28          // staged dim (16x16 out + halo 6)
#define SA 784         // 28*28

// Wave-level phase separator. __threadfence_block is a COMPILER memory fence
// (cross-lane LDS deps are invisible to the single-thread model; wave_barrier
// alone is IntrNoMem and lets LLVM hoist reads over writebacks). HW-side,
// same-wave DS ops are in-order; the fence's lgkmcnt drain is cheap.
__device__ __forceinline__ void wave_sync() {
    __builtin_amdgcn_wave_barrier();
    __threadfence_block();
    __builtin_amdgcn_wave_barrier();
}

__device__ __forceinline__ void ldrow8(const float* p, float* w) {
    const float4* q = (const float4*)p;
    float4 a = q[0], b = q[1];
    w[0] = a.x; w[1] = a.y; w[2] = a.z; w[3] = a.w;
    w[4] = b.x; w[5] = b.y; w[6] = b.z; w[7] = b.w;
}

// aligned 3xb128, window = floats [2,10) of the 12
__device__ __forceinline__ void ldrow12(const float* p, float* w) {
    const float4* q = (const float4*)p;
    float4 a = q[0], b = q[1], c = q[2];
    w[0] = a.z; w[1] = a.w; w[2] = b.x; w[3] = b.y;
    w[4] = b.z; w[5] = b.w; w[6] = c.x; w[7] = c.y;
}

// one row's contribution to 4 center px (centers at window idx 2..5)
__device__ __forceinline__ void contrib8(const float* gw, const float* xw, const float* yw,
                                         const float* ew, const float* cx, const float* cy,
                                         const float* ec, float* xr, float* yr) {
#pragma unroll
    for (int k = 0; k < 4; ++k) {
#pragma unroll
        for (int d = 0; d < 5; ++d) {
            int n = k + d;
            float dot = cx[k] * xw[n] + cy[k] * yw[n];
            float wm = __builtin_amdgcn_rcpf(1.f + ew[n] * ec[k]);
            float m = gw[n] * (wm * dot);
            xr[k] = fmaf(m, xw[n], xr[k]);
            yr[k] = fmaf(m, yw[n], yr[k]);
        }
    }
}

// compute unnormalized xr/yr for a 4-px group; WIDE=0 -> 8-float aligned window,
// WIDE=1 -> 12-float aligned read (centers still idx 2..5 of window)
template <int WIDE>
__device__ __forceinline__ void etf_group(const float* sg, const float* se,
                                          const float* sx, const float* sy,
                                          int base, float* xr, float* yr) {
    float cxw[8], cyw[8], cew[8];
    if (WIDE) { ldrow12(sx + base, cxw); ldrow12(sy + base, cyw); ldrow12(se + base, cew); }
    else      { ldrow8(sx + base, cxw);  ldrow8(sy + base, cyw);  ldrow8(se + base, cew); }
    float cx[4], cy[4], ec[4];
#pragma unroll
    for (int k = 0; k < 4; ++k) {
        cx[k] = cxw[k + 2];
        cy[k] = cyw[k + 2];
        ec[k] = __builtin_amdgcn_rcpf(cew[k + 2]);  // e^{+2 g_c/gmax}
    }
#pragma unroll
    for (int k = 0; k < 4; ++k) { xr[k] = 0.f; yr[k] = 0.f; }
#pragma unroll
    for (int dy = -2; dy <= 2; ++dy) {
        float gw[8], xw[8], yw[8], ew[8];
        int rb = base + dy * SS;
        if (WIDE) { ldrow12(sg + rb, gw); ldrow12(sx + rb, xw); ldrow12(sy + rb, yw); ldrow12(se + rb, ew); }
        else      { ldrow8(sg + rb, gw);  ldrow8(sx + rb, xw);  ldrow8(sy + rb, yw);  ldrow8(se + rb, ew); }
        contrib8(gw, xw, yw, ew, cx, cy, ec, xr, yr);
    }
}

// K2: all 3 ETF iterations, one 16x16 tile per WAVE, private LDS slice, no __syncthreads.
// Jacobi preserved: each phase computes into regs (rounds unrolled), then writes back.
__global__ __launch_bounds__(256, 3) void k_fused3(const float* __restrict__ g,
                                                   const float* __restrict__ xin,
                                                   const float* __restrict__ yin,
                                                   const float* __restrict__ gpart,
                                                   float* __restrict__ out,
                                                   double* __restrict__ partials) {
    __shared__ __align__(16) float lds[4 * 4 * SA];  // [wave][4 arrays][784]

    int tid = threadIdx.x;
    int wv = tid >> 6, lane = tid & 63;
    int ch = blockIdx.z;
    int txt = blockIdx.x * 4 + wv;   // x-tile 0..31
    int tyt = blockIdx.y;            // y-tile 0..31
    int bx0 = txt * 16, by0 = tyt * 16;

    float* sg = lds + wv * (4 * SA);
    float* se = sg + SA;
    float* sx = se + SA;
    float* sy = sx + SA;

    // per-wave gmax reduction from the 256 sobel-block partials.
    // After the butterfly all 64 lanes hold the max (wave-uniform; no readfirstlane —
    // the int-only builtin would TRUNCATE the float).
    const float* gp = gpart + ch * 256;
    float m = fmaxf(fmaxf(gp[lane], gp[lane + 64]), fmaxf(gp[lane + 128], gp[lane + 192]));
#pragma unroll
    for (int k = 32; k > 0; k >>= 1) m = fmaxf(m, __shfl_xor(m, k, 64));
    float s2 = -2.f * __builtin_amdgcn_rcpf(m);  // sigmoid(2d/gmax) = 0.5(1+tanh(d/gmax))

    // stage g/x/y with reflect halo 6; e computed inline
    const float* gc = g + (size_t)ch * HW;
    const float* xc = xin + (size_t)ch * HW;
    const float* yc = yin + (size_t)ch * HW;
    for (int i = lane; i < SA; i += 64) {
        int r = i / SS, c = i - r * SS;
        int yy = reflect_idx(by0 - 6 + r, H);
        int xx = reflect_idx(bx0 - 6 + c, W);
        int idx = yy * W + xx;
        float gv = gc[idx];
        sg[i] = gv;
        se[i] = __expf(s2 * gv);
        sx[i] = xc[idx];
        sy[i] = yc[idx];
    }
    wave_sync();

    // ---- iteration 1: centers rows [2,26) x cols [2,26); 24 rows x 6 groups = 144 units
    float o1x[3][4], o1y[3][4];
#pragma unroll
    for (int rnd = 0; rnd < 3; ++rnd) {
        int u = lane + rnd * 64;
        if (u < 144) {
            int gr = u / 6, gm = u - gr * 6;
            int base = (2 + gr) * SS + 4 * gm;  // window floats [4gm, 4gm+8)
            float xr[4], yr[4];
            etf_group<0>(sg, se, sx, sy, base, xr, yr);
#pragma unroll
            for (int k = 0; k < 4; ++k) {
                float iv = __builtin_amdgcn_rsqf(xr[k] * xr[k] + yr[k] * yr[k]);
                o1x[rnd][k] = xr[k] * iv;
                o1y[rnd][k] = yr[k] * iv;
            }
        }
    }
    wave_sync();
#pragma unroll
    for (int rnd = 0; rnd < 3; ++rnd) {
        int u = lane + rnd * 64;
        if (u < 144) {
            int gr = u / 6, gm = u - gr * 6;
            int c0 = (2 + gr) * SS + 2 + 4 * gm;
            *(float2*)&sx[c0] = make_float2(o1x[rnd][0], o1x[rnd][1]);
            *(float2*)&sx[c0 + 2] = make_float2(o1x[rnd][2], o1x[rnd][3]);
            *(float2*)&sy[c0] = make_float2(o1y[rnd][0], o1y[rnd][1]);
            *(float2*)&sy[c0 + 2] = make_float2(o1y[rnd][2], o1y[rnd][3]);
        }
    }
    wave_sync();

    // ---- iteration 2: centers rows [4,24) x cols [4,24); 20 rows x 5 groups = 100 units
    float o2x[2][4], o2y[2][4];
#pragma unroll
    for (int rnd = 0; rnd < 2; ++rnd) {
        int u = lane + rnd * 64;
        if (u < 100) {
            int gr = u / 5, gm = u - gr * 5;
            int base = (4 + gr) * SS + 4 * gm;  // 12-float read [4gm,4gm+12), window [2+4gm,10+4gm)
            float xr[4], yr[4];
            etf_group<1>(sg, se, sx, sy, base, xr, yr);
#pragma unroll
            for (int k = 0; k < 4; ++k) {
                float iv = __builtin_amdgcn_rsqf(xr[k] * xr[k] + yr[k] * yr[k]);
                o2x[rnd][k] = xr[k] * iv;
                o2y[rnd][k] = yr[k] * iv;
            }
        }
    }
    wave_sync();
#pragma unroll
    for (int rnd = 0; rnd < 2; ++rnd) {
        int u = lane + rnd * 64;
        if (u < 100) {
            int gr = u / 5, gm = u - gr * 5;
            int c0 = (4 + gr) * SS + 4 + 4 * gm;
            *(float2*)&sx[c0] = make_float2(o2x[rnd][0], o2x[rnd][1]);
            *(float2*)&sx[c0 + 2] = make_float2(o2x[rnd][2], o2x[rnd][3]);
            *(float2*)&sy[c0] = make_float2(o2y[rnd][0], o2y[rnd][1]);
            *(float2*)&sy[c0 + 2] = make_float2(o2y[rnd][2], o2y[rnd][3]);
        }
    }
    wave_sync();

    // ---- iteration 3: centers rows [6,22) x cols [6,22); 16 rows x 4 groups = 64 units
    double s = 0.0, q = 0.0;
    {
        int gm = lane & 3, gr = lane >> 2;
        int base = (6 + gr) * SS + 4 + 4 * gm;  // window [4+4gm, 12+4gm)
        float xr[4], yr[4];
        etf_group<0>(sg, se, sx, sy, base, xr, yr);

        float a[4];
#pragma unroll
        for (int k = 0; k < 4; ++k) {
            float ang = atanf(-yr[k] / xr[k]);  // normalization cancels in the ratio
            a[k] = (180.f * ang) / 3.14159274f;
            s += (double)a[k];
            q += (double)a[k] * (double)a[k];
        }
        float* oc = out + (size_t)ch * HW;
        *(float4*)(oc + (by0 + gr) * W + bx0 + 4 * gm) = make_float4(a[0], a[1], a[2], a[3]);
    }

    // per-wave shuffle reduction -> one partials slot per wave (no LDS, no barriers)
#pragma unroll
    for (int off = 32; off > 0; off >>= 1) {
        s += __shfl_down(s, off, 64);
        q += __shfl_down(q, off, 64);
    }
    if (lane == 0) {
        size_t slot = (size_t)ch * 1024 + tyt * 32 + txt;
        partials[slot * 2 + 0] = s;
        partials[slot * 2 + 1] = q;
    }
}

// ---------------- K3: instance norm (inline stats reduce over 1024 slots) ----------------
__global__ __launch_bounds__(256) void k_norm(float* __restrict__ a,
                                              const double* __restrict__ partials) {
    int ch = blockIdx.y;
    int t = threadIdx.x;

    double s = 0.0, q = 0.0;
#pragma unroll
    for (int k = 0; k < 4; ++k) {
        size_t i = (size_t)ch * 1024 + t * 4 + k;
        s += partials[i * 2 + 0];
        q += partials[i * 2 + 1];
    }
    __shared__ double rs[256], rq[256];
    rs[t] = s;
    rq[t] = q;
    __syncthreads();
    for (int st = 128; st > 0; st >>= 1) {
        if (t < st) {
            rs[t] += rs[t + st];
            rq[t] += rq[t + st];
        }
        __syncthreads();
    }
    __shared__ float sm, ss;
    if (t == 0) {
        double mean = rs[0] / (double)HW;
        double var = rq[0] / (double)HW - mean * mean;
        sm = (float)mean;
        ss = (float)(1.0 / sqrt(var + 1e-5));
    }
    __syncthreads();
    float mean = sm, sc = ss;

    float4* a4 = (float4*)(a + (size_t)ch * HW + (size_t)blockIdx.x * 4096);
#pragma unroll
    for (int k = 0; k < 4; ++k) {
        float4 v = a4[k * 256 + t];
        v.x = (v.x - mean) * sc;
        v.y = (v.y - mean) * sc;
        v.z = (v.z - mean) * sc;
        v.w = (v.w - mean) * sc;
        a4[k * 256 + t] = v;
    }
}

extern "C" void kernel_launch(void* const* d_in, const int* in_sizes, int n_in,
                              void* d_out, int out_size, void* d_ws, size_t ws_size,
                              hipStream_t stream) {
    (void)in_sizes; (void)n_in; (void)out_size; (void)ws_size;
    const float* img = (const float*)d_in[0];
    float* out = (float*)d_out;

    float* wsf = (float*)d_ws;
    float* gpart = wsf + 512;                       // 6*256 floats
    double* partials = (double*)(wsf + 8192);       // 6*1024*2 doubles = 96 KiB (ends at float 32768)
    float* g = wsf + 32768;                         // 3 fields of 6 MiB
    float* xnA = g + (size_t)NCH * HW;
    float* ynA = xnA + (size_t)NCH * HW;

    k_sobel<<<dim3(4, 64, NCH), dim3(32, 8), 0, stream>>>(img, gpart, g, xnA, ynA);
    k_fused3<<<dim3(8, 32, NCH), dim3(256), 0, stream>>>(g, xnA, ynA, gpart, out, partials);
    k_norm<<<dim3(64, NCH), dim3(256), 0, stream>>>(out, partials);
}

// Round 9
// 124.616 us; speedup vs baseline: 4.2426x; 4.2426x over previous
//
#include <hip/hip_runtime.h>
#include <math.h>

#define H 512
#define W 512
#define HW (H * W)
#define NCH 6

__device__ __forceinline__ int reflect_idx(int p, int n) {
    if (p < 0) p = -p;
    if (p >= n) p = 2 * n - 2 - p;
    return p;
}

// ---------------- K1: Sobel (LDS-tiled, 128x8, 4 px/thread interleaved) ----------------
// cmax (per-channel img max) dropped: pipeline is scale-invariant past the clamp;
// cmax only rescales the 1e-12 clamp threshold (~1e-6 effect). Sobel on RAW img.
__global__ __launch_bounds__(256) void k_sobel(const float* __restrict__ img,
                                               float* __restrict__ gpart,
                                               float* __restrict__ g,
                                               float* __restrict__ xn,
                                               float* __restrict__ yn) {
    const int SW = 132;  // stride; 130 cols used, 10 rows
    __shared__ float st[10 * SW];

    int ch = blockIdx.z;
    int bx0 = blockIdx.x * 128, by0 = blockIdx.y * 8;
    int tx = threadIdx.x, ty = threadIdx.y;
    int tid = ty * 32 + tx;
    const float* im = img + (size_t)ch * HW;

    // static staging: rows ty (+8 if ty<2), cols tx+32m (m=0..3) + tail tx<2 -> 128+tx
#pragma unroll
    for (int jr = 0; jr < 2; ++jr) {
        int r = ty + 8 * jr;
        if (jr == 0 || ty < 2) {
            int yy = by0 - 1 + r;
            bool yok = (yy >= 0 && yy < H);
            const float* rowp = im + yy * W;
#pragma unroll
            for (int m = 0; m < 4; ++m) {
                int c = tx + 32 * m;
                int xx = bx0 - 1 + c;
                float v = 0.f;
                if (yok && xx >= 0 && xx < W) v = rowp[xx];
                st[r * SW + c] = v;
            }
            if (tx < 2) {
                int c = 128 + tx;
                int xx = bx0 - 1 + c;
                float v = 0.f;
                if (yok && xx >= 0 && xx < W) v = rowp[xx];
                st[r * SW + c] = v;
            }
        }
    }
    __syncthreads();

    float bmax = 0.f;
    int y = by0 + ty;
    int r = ty + 1;
    float gm4[4], xr4[4], yr4[4];
#pragma unroll
    for (int k = 0; k < 4; ++k) {
        int c = tx + 32 * k + 1;
        float a00 = st[(r - 1) * SW + c - 1], a01 = st[(r - 1) * SW + c], a02 = st[(r - 1) * SW + c + 1];
        float a10 = st[r * SW + c - 1], a12 = st[r * SW + c + 1];
        float a20 = st[(r + 1) * SW + c - 1], a21 = st[(r + 1) * SW + c], a22 = st[(r + 1) * SW + c + 1];

        float gx = (a02 - a00) + 2.f * (a12 - a10) + (a22 - a20);
        float gy = (a20 - a00) + 2.f * (a21 - a01) + (a22 - a02);

        gx = fmaxf(gx, 1e-12f);
        gy = fmaxf(gy, 1e-12f);
        float d = gx * gx + gy * gy;
        float rq = __builtin_amdgcn_rsqf(d);
        float gm = d * rq;
        float xv = gx * rq, yv = gy * rq;
        const float ct = -4.37113883e-08f;  // cosf(fp32 pi/2); sin = 1.0 exactly
        gm4[k] = gm;
        xr4[k] = xv * ct - yv;
        yr4[k] = yv * ct + xv;
        bmax = fmaxf(bmax, gm);
    }
#pragma unroll
    for (int k = 0; k < 4; ++k) {
        int idx = y * W + bx0 + tx + 32 * k;
        float* gc = g + (size_t)ch * HW;
        float* xc = xn + (size_t)ch * HW;
        float* yc = yn + (size_t)ch * HW;
        gc[idx] = gm4[k];
        xc[idx] = xr4[k];
        yc[idx] = yr4[k];
    }

    __syncthreads();
    st[tid] = bmax;
    __syncthreads();
    for (int s = 128; s > 0; s >>= 1) {
        if (tid < s) st[tid] = fmaxf(st[tid], st[tid + s]);
        __syncthreads();
    }
    if (tid == 0) gpart[ch * 256 + blockIdx.y * 4 + blockIdx.x] = st[0];
}

// ---------------- K1b: reduce 256 partials -> gmax[ch] ----------------
__global__ __launch_bounds__(64) void k_red(const float* __restrict__ gpart,
                                            float* __restrict__ gmax) {
    int ch = blockIdx.x;
    int t = threadIdx.x;
    const float* gp = gpart + ch * 256;
    float m = fmaxf(fmaxf(gp[t], gp[t + 64]), fmaxf(gp[t + 128], gp[t + 192]));
#pragma unroll
    for (int k = 32; k > 0; k >>= 1) m = fmaxf(m, __shfl_xor(m, k, 64));
    if (t == 0) gmax[ch] = m;
}

struct W8 { float w[8]; };

// ---------------- K2: one ETF iteration, 4 px/thread (LAST fuses angle+partials) -------
template <bool LAST>
__global__ __launch_bounds__(256) void k_iter(const float* __restrict__ g,
                                              const float* __restrict__ xin,
                                              const float* __restrict__ yin,
                                              const float* __restrict__ gmaxp,
                                              float* __restrict__ xout,
                                              float* __restrict__ yout,
                                              double* __restrict__ partials) {
    const int SW = 136;  // stride; tile 128x8 + halo 2 -> 132 cols used, 12 rows
    __shared__ __align__(16) float sg[12 * SW];
    __shared__ __align__(16) float se[12 * SW];
    __shared__ __align__(16) float sx[12 * SW];
    __shared__ __align__(16) float sy[12 * SW];
    __shared__ double swr[8];

    int ch = blockIdx.z;
    int bx0 = blockIdx.x * 128, by0 = blockIdx.y * 8;
    int tx = threadIdx.x, ty = threadIdx.y;
    int tid = ty * 32 + tx;
    const size_t cbase = (size_t)ch * HW;

    float s2 = -2.f * __builtin_amdgcn_rcpf(gmaxp[ch]);  // sigmoid(2d/gmax)=0.5(1+tanh(d/gmax))

    // static staging: rows ty (+8 if ty<4), cols tx+32m (m=0..3) + tail tx<4 -> 128+tx
    const float* gc = g + cbase;
    const float* xc = xin + cbase;
    const float* yc = yin + cbase;
#pragma unroll
    for (int jr = 0; jr < 2; ++jr) {
        int r = ty + 8 * jr;
        if (jr == 0 || ty < 4) {
            int yy = reflect_idx(by0 - 2 + r, H);
            const float* grow = gc + yy * W;
            const float* xrow = xc + yy * W;
            const float* yrow = yc + yy * W;
#pragma unroll
            for (int m = 0; m < 5; ++m) {
                int c = (m < 4) ? (tx + 32 * m) : (128 + tx);
                if (m < 4 || tx < 4) {
                    int xx = reflect_idx(bx0 - 2 + c, W);
                    int s = r * SW + c;
                    float gv = grow[xx];
                    sg[s] = gv;
                    se[s] = __expf(s2 * gv);
                    sx[s] = xrow[xx];
                    sy[s] = yrow[xx];
                }
            }
        }
    }
    __syncthreads();

    // thread handles pixels x = bx0 + 4*tx + k, k=0..3; LDS center col = 4*tx+2+k
    auto LD8 = [&](const float* s, int r) {
        W8 o;
        const float4* p = (const float4*)(s + r * SW + 4 * tx);
        float4 a = p[0], b = p[1];
        o.w[0] = a.x; o.w[1] = a.y; o.w[2] = a.z; o.w[3] = a.w;
        o.w[4] = b.x; o.w[5] = b.y; o.w[6] = b.z; o.w[7] = b.w;
        return o;
    };

    int row0 = ty + 2;
    W8 cxw = LD8(sx, row0), cyw = LD8(sy, row0), cew = LD8(se, row0);
    float cx[4], cy[4], ec[4];
#pragma unroll
    for (int k = 0; k < 4; ++k) {
        cx[k] = cxw.w[k + 2];
        cy[k] = cyw.w[k + 2];
        ec[k] = __builtin_amdgcn_rcpf(cew.w[k + 2]);  // e^{+2 g_c/gmax}
    }

    float xr[4] = {0.f, 0.f, 0.f, 0.f}, yr[4] = {0.f, 0.f, 0.f, 0.f};
#pragma unroll
    for (int dy = -2; dy <= 2; ++dy) {
        W8 gw = LD8(sg, row0 + dy), xw = LD8(sx, row0 + dy),
           yw = LD8(sy, row0 + dy), ew = LD8(se, row0 + dy);
#pragma unroll
        for (int k = 0; k < 4; ++k) {
#pragma unroll
            for (int dxi = 0; dxi < 5; ++dxi) {
                int n = k + dxi;
                float dot = cx[k] * xw.w[n] + cy[k] * yw.w[n];
                float wm = __builtin_amdgcn_rcpf(1.f + ew.w[n] * ec[k]);
                float m = gw.w[n] * (wm * dot);
                xr[k] = fmaf(m, xw.w[n], xr[k]);
                yr[k] = fmaf(m, yw.w[n], yr[k]);
            }
        }
    }

    size_t obase = cbase + (size_t)(by0 + ty) * W + bx0 + 4 * tx;
    if (!LAST) {
        float ox[4], oy[4];
#pragma unroll
        for (int k = 0; k < 4; ++k) {
            float im2 = __builtin_amdgcn_rsqf(xr[k] * xr[k] + yr[k] * yr[k]);
            ox[k] = xr[k] * im2;
            oy[k] = yr[k] * im2;
        }
        *(float4*)(xout + obase) = make_float4(ox[0], ox[1], ox[2], ox[3]);
        *(float4*)(yout + obase) = make_float4(oy[0], oy[1], oy[2], oy[3]);
    } else {
        // normalization cancels in the ratio: angle = atan(-yr/xr)
        float a[4];
        double s = 0.0, q = 0.0;
#pragma unroll
        for (int k = 0; k < 4; ++k) {
            float ang = atanf(-yr[k] / xr[k]);
            a[k] = (180.f * ang) / 3.14159274f;
            s += (double)a[k];
            q += (double)a[k] * (double)a[k];
        }
        *(float4*)(xout + obase) = make_float4(a[0], a[1], a[2], a[3]);

        // wave shuffle-reduce, then 4 leaders through LDS
#pragma unroll
        for (int off = 32; off > 0; off >>= 1) {
            s += __shfl_down(s, off, 64);
            q += __shfl_down(q, off, 64);
        }
        if ((tid & 63) == 0) {
            swr[tid >> 6] = s;
            swr[4 + (tid >> 6)] = q;
        }
        __syncthreads();
        if (tid == 0) {
            double ts = swr[0] + swr[1] + swr[2] + swr[3];
            double tq = swr[4] + swr[5] + swr[6] + swr[7];
            int blk = blockIdx.y * 4 + blockIdx.x;  // 256 blocks per channel
            partials[((size_t)ch * 256 + blk) * 2 + 0] = ts;
            partials[((size_t)ch * 256 + blk) * 2 + 1] = tq;
        }
    }
}

// ---------------- K3: instance norm (inline stats reduce, then normalize) ----------------
__global__ __launch_bounds__(256) void k_norm(float* __restrict__ a,
                                              const double* __restrict__ partials) {
    int ch = blockIdx.y;
    int t = threadIdx.x;

    __shared__ double rs[256], rq[256];
    rs[t] = partials[((size_t)ch * 256 + t) * 2 + 0];
    rq[t] = partials[((size_t)ch * 256 + t) * 2 + 1];
    __syncthreads();
    for (int st = 128; st > 0; st >>= 1) {
        if (t < st) {
            rs[t] += rs[t + st];
            rq[t] += rq[t + st];
        }
        __syncthreads();
    }
    __shared__ float sm, ss;
    if (t == 0) {
        double mean = rs[0] / (double)HW;
        double var = rq[0] / (double)HW - mean * mean;
        sm = (float)mean;
        ss = (float)(1.0 / sqrt(var + 1e-5));
    }
    __syncthreads();
    float mean = sm, sc = ss;

    float4* a4 = (float4*)(a + (size_t)ch * HW + (size_t)blockIdx.x * 4096);
#pragma unroll
    for (int k = 0; k < 4; ++k) {
        float4 v = a4[k * 256 + t];
        v.x = (v.x - mean) * sc;
        v.y = (v.y - mean) * sc;
        v.z = (v.z - mean) * sc;
        v.w = (v.w - mean) * sc;
        a4[k * 256 + t] = v;
    }
}

extern "C" void kernel_launch(void* const* d_in, const int* in_sizes, int n_in,
                              void* d_out, int out_size, void* d_ws, size_t ws_size,
                              hipStream_t stream) {
    (void)in_sizes; (void)n_in; (void)out_size; (void)ws_size;
    const float* img = (const float*)d_in[0];
    float* out = (float*)d_out;

    float* wsf = (float*)d_ws;
    float* gmax = wsf + 8;                          // [6]
    float* gpart = wsf + 512;                       // 6*256
    double* partials = (double*)(wsf + 8192);       // 6*256*2 doubles
    float* g = wsf + 32768;                         // 5 fields of 6 MiB
    float* xnA = g + (size_t)NCH * HW;
    float* ynA = xnA + (size_t)NCH * HW;
    float* xnB = ynA + (size_t)NCH * HW;
    float* ynB = xnB + (size_t)NCH * HW;

    dim3 tile_grid(4, 64, NCH), tile_blk(32, 8);

    k_sobel<<<tile_grid, tile_blk, 0, stream>>>(img, gpart, g, xnA, ynA);
    k_red<<<dim3(NCH), dim3(64), 0, stream>>>(gpart, gmax);
    k_iter<false><<<tile_grid, tile_blk, 0, stream>>>(g, xnA, ynA, gmax, xnB, ynB, nullptr);
    k_iter<false><<<tile_grid, tile_blk, 0, stream>>>(g, xnB, ynB, gmax, xnA, ynA, nullptr);
    k_iter<true><<<tile_grid, tile_blk, 0, stream>>>(g, xnA, ynA, gmax, out, nullptr, partials);
    k_norm<<<dim3(64, NCH), dim3(256), 0, stream>>>(out, partials);
}